// Round 16
// baseline (165.906 us; speedup 1.0000x reference)
//
#include <hip/hip_runtime.h>
#include <stdint.h>

#define N_PTS 2048
#define NK 5
#define TOPK 512
#define CAP_MAX 262144u
#define GLIST_CAP 256
#define T0_BITS 0x3F700000u          /* 0.9375f — static list threshold */

// frozen arithmetic (r9-verified bit-exact vs np oracle):
//   d2 = fma(dz,dz, fma(dx,dx, dy*dy)); d = sqrt(max(d2,0))
//   q = fdiv(diff*diff, 0.01f); temp = max(1-q,0); v = (L*temp)*A
// tie rule: value desc, flat idx asc (key (vb<<32)|~idx descending)
// rejection bounds (exact): v <= fmul_rn(Lsr,temp) <= Lsr
// div-free cell pre-gate (exact, RN-monotone):
//   temp <= fma(dsq,-99,1) = ts  =>  RN(Lsr*ts) = ubt >= ub >= v
// latency rule (r4): no gather-dependent value in the gate of the next gather.
// gather rule (r12): gate gathers with a running wave max (exact pruning).
// serialization rule (r5/r16): no serial per-bin scans on one lane; wave-split
//   histograms; ballot-aggregated queue pushes; and no multi-barrier sorts in
//   single-block kernels — rank-by-count (1 barrier) replaces bitonic (45).
// threshold relaxation (r6/r7/r13): T' = lower edge of the 256-bin
//   lb-histogram bin where the from-top cumulative crosses 512; candidate
//   superset => select's exact top-512 bit-identical. Derived per block in
//   collect; no grid sync.
// launch rule (r7): no cooperative launch / grid.sync under this harness.
// anchor rule (r9/r12): revert to best measured + ONE delta after failure.
// harness floor (r9/r14): ws re-poison fills ~86us/iter untouchable;
//   controllable budget ~72us. collect measured 21-22us (r14 probe) and is
//   NOT stream-bound (r15 null).
// balance rule (r10): compact survivors (LDS queue) + cell-parallel.
// fragmentation rule (r13): per-dispatch overhead ~3us — minimize kernels.
// attribution rule (r14/r16): measure or isolate before theorizing; bundled
//   changes (r11) must be re-tested one at a time.
// list rule (r15): lowb emits per-row survivor lists at static T0; collect
//   skips its L-stream when T' >= T0 and no overflow; else full-row path.

// ws layout (bytes):
//      0  src_ne_idx   int[10240]    (40960)
//  40960  src_ne_dist  f32[10240]    (40960)
//  81920  ref_ne_idx   int[10240]    (40960)
// 122880  ref_ne_dist  f32[10240]    (40960)
// 163840  hist         uint[256]     (1024)  (lb histogram; zeroed by knn)
// 172032  counters     uint[8]       (32)    [0]=cand_count (zeroed by knn)
// 172064  cand         uint64[CAP_MAX]               (2MB)
// 2269216 glist        uint64[2048*GLIST_CAP]        (4MB)  (Lsr<<32|col)
// 6463520 gcnt         uint[2048]                    (8KB)
#define OFF_SIDX   0
#define OFF_SDIST  40960
#define OFF_RIDX   81920
#define OFF_RDIST  122880
#define OFF_HIST   163840
#define OFF_CNT    172032
#define OFF_CAND   172064
#define OFF_GLIST  2269216
#define OFF_GCNT   6463520
#define WS_NEED    6471712ull

__device__ __forceinline__ unsigned long long shflxor64(unsigned long long v, int mask) {
  unsigned lo = (unsigned)v, hi = (unsigned)(v >> 32);
  lo = (unsigned)__shfl_xor((int)lo, mask);
  hi = (unsigned)__shfl_xor((int)hi, mask);
  return ((unsigned long long)hi << 32) | lo;
}

__device__ __forceinline__ int lb_bin(unsigned int bits) {
  int b = (int)(bits >> 16) - 0x3E80;
  return b < 0 ? 0 : (b > 255 ? 255 : b);
}

// ---------------- KNN: 512 blocks, 8 points/block, 32 lanes/point ------------
__global__ __launch_bounds__(256) void knn_kernel(
    const float* __restrict__ src, const float* __restrict__ ref,
    int* __restrict__ sidx, float* __restrict__ sdist,
    int* __restrict__ ridx, float* __restrict__ rdist,
    unsigned int* __restrict__ hist, unsigned int* __restrict__ counters) {
  __shared__ float sx[N_PTS], sy[N_PTS], sz[N_PTS];
  const bool is_ref = blockIdx.x >= 256;
  const float* pts = is_ref ? ref : src;
  int*   oidx  = is_ref ? ridx : sidx;
  float* odist = is_ref ? rdist : sdist;
  const int blk = is_ref ? (blockIdx.x - 256) : blockIdx.x;

  if (blockIdx.x == 0) {
    if (threadIdx.x < 256) hist[threadIdx.x] = 0;
    if (threadIdx.x < 8) counters[threadIdx.x] = 0;
  }

  for (int t = threadIdx.x; t < N_PTS; t += 256) {
    sx[t] = pts[3 * t + 0];
    sy[t] = pts[3 * t + 1];
    sz[t] = pts[3 * t + 2];
  }
  __syncthreads();

  const int p = blk * 8 + (threadIdx.x >> 5);
  const int u = threadIdx.x & 31;
  const float px = sx[p], py = sy[p], pz = sz[p];

  unsigned long long best[6];
#pragma unroll
  for (int k = 0; k < 6; ++k) best[k] = ~0ull;

  for (int j = u; j < N_PTS; j += 32) {
    float dx = __fsub_rn(px, sx[j]);
    float dy = __fsub_rn(py, sy[j]);
    float dz = __fsub_rn(pz, sz[j]);
    float d2 = __builtin_fmaf(dz, dz,
                 __builtin_fmaf(dx, dx, __fmul_rn(dy, dy)));
    float d = __fsqrt_rn(fmaxf(d2, 0.0f));
    unsigned long long key = (((unsigned long long)__float_as_uint(d)) << 32)
                           | (unsigned)j;
    if (key < best[5]) {
      best[5] = key;
#pragma unroll
      for (int k = 5; k >= 1; --k)
        if (best[k] < best[k - 1]) {
          unsigned long long t = best[k]; best[k] = best[k - 1]; best[k - 1] = t;
        }
    }
  }

  int h = 0;
  unsigned long long win[6];
#pragma unroll
  for (int round = 0; round < 6; ++round) {
    unsigned long long my = (h < 6) ? best[h] : ~0ull;
    unsigned long long m = my;
#pragma unroll
    for (int msk = 16; msk >= 1; msk >>= 1) {
      unsigned long long o = shflxor64(m, msk);
      if (o < m) m = o;
    }
    win[round] = m;
    if (my == m) ++h;
  }

  if (u == 0) {
#pragma unroll
    for (int m = 1; m <= NK; ++m) {     // drop win[0] == self (d = 0)
      oidx[p * NK + m - 1]  = (int)(win[m] & 0xFFFFFFFFull);
      odist[p * NK + m - 1] = __uint_as_float((unsigned)(win[m] >> 32));
    }
  }
}

// ---------------- pass 1: lower bound -> histogram, + survivor list (r15) ----
__global__ __launch_bounds__(256) void lowb_kernel(
    const float* __restrict__ L,
    const int* __restrict__ sidx, const float* __restrict__ sdist,
    const int* __restrict__ ridx, const float* __restrict__ rdist,
    unsigned int* __restrict__ hist,
    uint64_t* __restrict__ glist, unsigned int* __restrict__ gcnt,
    int use_list) {
  __shared__ float sdsh[NK];
  __shared__ int   snsh[NK];
  __shared__ unsigned int s_max;
  __shared__ unsigned int lqn;
  const int s = blockIdx.x, tid = threadIdx.x;
  const int lane = tid & 63;
  if (tid < NK) { snsh[tid] = sidx[s * NK + tid]; sdsh[tid] = sdist[s * NK + tid]; }
  if (tid == 0) { s_max = 0; lqn = 0; }
  __syncthreads();                             // lqn=0 visible before pushes
  const float* __restrict__ Lg = L + (size_t)s * N_PTS;
  const float T0f = __uint_as_float(T0_BITS);

  // per-thread top-3 over its 8 contiguous columns + list push
  unsigned long long b0 = 0ull, b1 = 0ull, b2 = 0ull;
  {
    const float4* Lg4 = (const float4*)Lg;
    float4 A0 = Lg4[2 * tid], A1 = Lg4[2 * tid + 1];
    float lv[8] = {A0.x, A0.y, A0.z, A0.w, A1.x, A1.y, A1.z, A1.w};
#pragma unroll
    for (int e = 0; e < 8; ++e) {
      unsigned long long key =
          (((unsigned long long)__float_as_uint(lv[e])) << 32)
          | (unsigned)(tid * 8 + e);           // L >= 0: bit order == value order
      if (key > b0) { b2 = b1; b1 = b0; b0 = key; }
      else if (key > b1) { b2 = b1; b1 = key; }
      else if (key > b2) b2 = key;
      const bool qp = use_list && (lv[e] >= T0f);
      unsigned long long m = __ballot(qp);
      if (qp) {
        const int leader = __ffsll((long long)m) - 1;
        unsigned int base = 0;
        if (lane == leader) base = atomicAdd(&lqn, (unsigned int)__popcll(m));
        base = (unsigned int)__shfl((int)base, leader);
        const unsigned int pos =
            base + (unsigned int)__popcll(m & ((1ull << lane) - 1ull));
        if (pos < GLIST_CAP)
          glist[(size_t)s * GLIST_CAP + pos] =
              (((uint64_t)__float_as_uint(lv[e])) << 32)
              | (uint64_t)(unsigned)(tid * 8 + e);
      }
    }
  }
  __syncthreads();                             // sdsh/snsh + list pushes done

  unsigned int lmw = 0;                        // running wave max (uniform)
  int h = 0;
  for (int round = 0; round < 3; ++round) {
    unsigned long long my = (h == 0) ? b0 : ((h == 1) ? b1 : ((h == 2) ? b2 : 0ull));
    unsigned long long w = my;
#pragma unroll
    for (int msk = 32; msk >= 1; msk >>= 1) {
      unsigned long long o = shflxor64(w, msk);
      if (o > w) w = o;
    }
    if (my == w && w != 0ull) ++h;             // unique keys (r embedded)
    if ((unsigned)(w >> 32) == 0u) continue;
    const int rwin = (int)(w & 0xFFFFFFFFull);
    const float Lsr = __uint_as_float((unsigned)(w >> 32));
    unsigned int vb = 0;
    if (lane < NK * NK) {
      const int i = lane / NK, j = lane - i * NK;
      float diff = __fsub_rn(sdsh[i], rdist[rwin * NK + j]);  // frozen chain
      float dsq  = __fmul_rn(diff, diff);
      if (dsq < 0.0101f) {
        float ts  = __builtin_fmaf(dsq, -99.0f, 1.0f);        // >= temp (exact)
        float ubt = __fmul_rn(Lsr, ts);                       // >= ub >= v
        if (ubt > __uint_as_float(lmw)) {                     // running-max gate
          float q    = __fdiv_rn(dsq, 0.01f);
          float temp = fmaxf(__fsub_rn(1.0f, q), 0.0f);
          if (temp > 0.0f) {
            float ub = __fmul_rn(Lsr, temp);
            float a  = L[(size_t)snsh[i] * N_PTS + ridx[rwin * NK + j]];
            float v  = __fmul_rn(ub, a);                      // frozen chain
            if (v > 0.0f) vb = __float_as_uint(v);
          }
        }
      }
    }
#pragma unroll
    for (int msk = 32; msk >= 1; msk >>= 1) {
      unsigned int o = (unsigned)__shfl_xor((int)vb, msk);
      if (o > vb) vb = o;
    }
    if (vb > lmw) lmw = vb;                    // uniform across wave
  }
  if (lane == 0 && lmw > 0u) atomicMax(&s_max, lmw);
  __syncthreads();
  if (tid == 0) {
    atomicAdd(&hist[lb_bin(s_max)], 1u);
    if (use_list) gcnt[s] = lqn;
  }
}

// ---------------- pass 2: collect — list fast path or full-row (r15/r13) -----
__global__ __launch_bounds__(256) void collect_kernel(
    const float* __restrict__ L,
    const int* __restrict__ sidx, const float* __restrict__ sdist,
    const int* __restrict__ ridx, const float* __restrict__ rdist,
    const unsigned int* __restrict__ hist,
    const uint64_t* __restrict__ glist, const unsigned int* __restrict__ gcnt,
    int use_list,
    unsigned int* __restrict__ cand_count, uint64_t* __restrict__ cand,
    unsigned int cap) {
  __shared__ float sdsh[NK];
  __shared__ int   snsh[NK];
  __shared__ int   q_r[N_PTS];
  __shared__ float q_L[N_PTS];
  __shared__ unsigned int qn;
  __shared__ unsigned int sh_T;
  const int s = blockIdx.x, tid = threadIdx.x;
  const int lane = tid & 63;
  if (tid < NK) { snsh[tid] = sidx[s * NK + tid]; sdsh[tid] = sdist[s * NK + tid]; }
  if (tid == 0) qn = 0;

  // ---- wave 0: derive T' from histogram (r5 scan; crossing always exists) --
  if (tid < 64) {
    const int b0i = tid * 4;
    unsigned int c0 = hist[b0i + 0], c1 = hist[b0i + 1];
    unsigned int c2 = hist[b0i + 2], c3 = hist[b0i + 3];
    const unsigned int S = c0 + c1 + c2 + c3;
    unsigned int si = S;                       // inclusive suffix over lanes
#pragma unroll
    for (int off = 1; off < 64; off <<= 1) {
      unsigned int o = (unsigned)__shfl_down((int)si, off);
      si += (tid + off < 64) ? o : 0u;
    }
    const unsigned int SE = si - S;
    const unsigned int k = TOPK;
    const unsigned int s3 = SE + c3;
    const unsigned int s2 = s3 + c2;
    const unsigned int s1 = s2 + c1;
    const unsigned int s0 = s1 + c0;
    int b = -1;
    if      (s0 >= k && s1 < k) b = b0i + 0;
    else if (s1 >= k && s2 < k) b = b0i + 1;
    else if (s2 >= k && s3 < k) b = b0i + 2;
    else if (s3 >= k && SE < k) b = b0i + 3;
    if (b >= 0)
      sh_T = (b > 0) ? (((unsigned int)(0x3E80 + b)) << 16) : 0u;
  }
  __syncthreads();                             // sh_T, qn, sdsh/snsh visible
  const unsigned int T = sh_T;
  const float T_f = __uint_as_float(T);

  // ---- phase A: build survivor queue (fast: from glist; slow: full row) ----
  const unsigned int gc = use_list ? gcnt[s] : 0xFFFFFFFFu;  // broadcast load
  const bool fast = use_list && (T >= T0_BITS) && (gc <= GLIST_CAP);
  if (fast) {
    bool have = false; int col = 0; float Ls = 0.0f;
    if ((unsigned int)tid < gc) {
      uint64_t e = glist[(size_t)s * GLIST_CAP + tid];
      Ls  = __uint_as_float((unsigned int)(e >> 32));
      col = (int)(unsigned int)(e & 0xFFFFFFFFull);
      have = (Ls >= T_f);                      // exact filter: {r: Lsr >= T'}
    }
    unsigned long long m = __ballot(have);
    if (have) {
      const int leader = __ffsll((long long)m) - 1;
      unsigned int base = 0;
      if (lane == leader) base = atomicAdd(&qn, (unsigned int)__popcll(m));
      base = (unsigned int)__shfl((int)base, leader);
      const unsigned int off =
          (unsigned int)__popcll(m & ((1ull << lane) - 1ull));
      q_r[base + off] = col;
      q_L[base + off] = Ls;
    }
  } else {
    const float4* Lg4 = (const float4*)(L + (size_t)s * N_PTS);
    float4 A0 = Lg4[2 * tid], A1 = Lg4[2 * tid + 1];
    float lv[8] = {A0.x, A0.y, A0.z, A0.w, A1.x, A1.y, A1.z, A1.w};
#pragma unroll
    for (int e = 0; e < 8; ++e) {
      const float Lsr = lv[e];
      const bool surv = (Lsr >= T_f);          // v <= Lsr < T' => reject rest
      unsigned long long mask = __ballot(surv);
      if (surv) {
        const int leader = __ffsll((long long)mask) - 1;
        unsigned int base = 0;
        if (lane == leader) base = atomicAdd(&qn, (unsigned int)__popcll(mask));
        base = (unsigned int)__shfl((int)base, leader);
        const unsigned int off =
            (unsigned int)__popcll(mask & ((1ull << lane) - 1ull));
        q_r[base + off] = tid * 8 + e;
        q_L[base + off] = Lsr;
      }
    }
  }
  __syncthreads();
  const unsigned int nq = qn;

  // ---- phase B: cell-parallel processing, 8 groups x 32 lanes ----
  const int g = tid >> 5, l32 = tid & 31;
  const bool cell = (l32 < NK * NK);
  const int ci = cell ? (l32 / NK) : 0;
  const int cj = cell ? (l32 - ci * NK) : 0;
  const float sd_i = sdsh[ci];
  const float* __restrict__ Arow = L + (size_t)snsh[ci] * N_PTS;

  for (unsigned int base = 0; base < nq; base += 8) {
    const unsigned int qi = base + (unsigned int)g;
    if (qi >= nq) break;                       // group-uniform; no barriers here
    const int r = q_r[qi];
    const float Lsr = q_L[qi];
    if (cell) {
      float rdv  = rdist[r * NK + cj];
      float diff = __fsub_rn(sd_i, rdv);
      float dsq  = __fmul_rn(diff, diff);
      if (dsq < 0.0101f) {                               // else temp provably 0
        float ts  = __builtin_fmaf(dsq, -99.0f, 1.0f);   // >= temp (exact)
        float ubt = __fmul_rn(Lsr, ts);                  // >= ub >= v
        if (ubt >= T_f) {                                // div-free pre-gate
          float q    = __fdiv_rn(dsq, 0.01f);
          float temp = fmaxf(__fsub_rn(1.0f, q), 0.0f);
          if (temp > 0.0f) {
            float ub = __fmul_rn(Lsr, temp);
            if (ub >= T_f) {                             // v <= ub < T' reject
              int   rn = ridx[r * NK + cj];
              float v  = __fmul_rn(ub, Arow[rn]);        // frozen chain
              unsigned int vb = __float_as_uint(v);
              if (v > 0.0f && vb >= T) {
                unsigned int pos = atomicAdd(cand_count, 1u);
                if (pos < cap) {
                  unsigned int idx = ((unsigned int)s * (unsigned int)N_PTS
                                      + (unsigned int)r) * 25u
                                   + (unsigned int)ci * 5u + (unsigned int)cj;
                  cand[pos] = (((uint64_t)vb) << 32)
                            | (uint64_t)((uint32_t)(~idx));
                }
              }
            }
          }
        }
      }
    }
  }
}

// ---------------- exact top-512: byte radix-select + rank-by-count (r16) -----
// r5: 16-way wave-split histogram + wave-0 register suffix-scan bin select.
// r16: output ordering via rank-by-count (1 barrier, broadcast LDS loop)
// instead of bitonic (45 barriers). kstar = exact 512th key of UNIQUE keys
// => cnt2 == 512, all topk slots real, rank is a permutation; slot tie-break
// keeps it a permutation even for degenerate duplicates (identical decoded
// outputs). Mapping (descending by key) identical to bitonic's.
__global__ __launch_bounds__(1024) void select_kernel(
    const uint64_t* __restrict__ cand, const unsigned int* __restrict__ counters,
    const int* __restrict__ sidx, const int* __restrict__ ridx,
    int* __restrict__ out, unsigned int cap) {
  __shared__ unsigned int h[16][257];          // wave-split histogram, padded
  __shared__ uint64_t topk[TOPK];
  __shared__ unsigned int cnt2;
  __shared__ uint64_t sh_prefix;
  __shared__ unsigned int sh_k;
  const int tid = threadIdx.x;
  const int wv = tid >> 6;
  unsigned int n = counters[0];
  if (n > cap) n = cap;
  if (tid == 0) { sh_prefix = 0; sh_k = TOPK; cnt2 = 0; }
  unsigned int* hflat = &h[0][0];

  for (int byte = 7; byte >= 0; --byte) {
    for (int t = tid; t < 16 * 257; t += 1024) hflat[t] = 0;
    __syncthreads();
    const uint64_t prefix = sh_prefix;
    const uint64_t mask = (byte == 7) ? 0ull : (~0ull << (8 * (byte + 1)));
    for (unsigned int i = tid; i < n; i += 1024) {
      uint64_t key = cand[i];
      if ((key & mask) == prefix)
        atomicAdd(&h[wv][(unsigned int)(key >> (8 * byte)) & 255u], 1u);
    }
    __syncthreads();
    if (tid < 64) {                            // wave 0: parallel bin select
      const int b0i = tid * 4;
      unsigned int c0 = 0, c1 = 0, c2 = 0, c3 = 0;
#pragma unroll
      for (int w = 0; w < 16; ++w) {
        c0 += h[w][b0i + 0]; c1 += h[w][b0i + 1];
        c2 += h[w][b0i + 2]; c3 += h[w][b0i + 3];
      }
      const unsigned int S = c0 + c1 + c2 + c3;
      unsigned int si = S;                     // inclusive suffix over lanes
#pragma unroll
      for (int off = 1; off < 64; off <<= 1) {
        unsigned int o = (unsigned)__shfl_down((int)si, off);
        si += (tid + off < 64) ? o : 0u;
      }
      const unsigned int SE = si - S;          // suffix-exclusive of this lane
      const unsigned int k = sh_k;
      const unsigned int s3 = SE + c3;
      const unsigned int s2 = s3 + c2;
      const unsigned int s1 = s2 + c1;
      const unsigned int s0 = s1 + c0;
      int b = -1; unsigned int kn = 0;
      if      (s0 >= k && s1 < k) { b = b0i + 0; kn = k - s1; }
      else if (s1 >= k && s2 < k) { b = b0i + 1; kn = k - s2; }
      else if (s2 >= k && s3 < k) { b = b0i + 2; kn = k - s3; }
      else if (s3 >= k && SE < k) { b = b0i + 3; kn = k - SE; }
      unsigned long long bal = __ballot(b >= 0);
      if (b >= 0) {
        sh_prefix = prefix | (((uint64_t)(unsigned)b) << (8 * byte));
        sh_k = kn;
      } else if (tid == 0 && bal == 0ull) {
        sh_prefix = prefix;                    // degenerate: chosen=0, k kept
      }
    }
    __syncthreads();
  }
  const uint64_t kstar = sh_prefix;

  for (int t = tid; t < TOPK; t += 1024) topk[t] = 0;
  __syncthreads();
  for (unsigned int i = tid; i < n; i += 1024) {
    uint64_t key = cand[i];
    if (key >= kstar) {
      unsigned int pos = atomicAdd(&cnt2, 1u);
      if (pos < TOPK) topk[pos] = key;
    }
  }
  __syncthreads();

  if (tid < TOPK) {
    const uint64_t key = topk[tid];
    int rank = 0;
    for (int m = 0; m < TOPK; ++m) {
      uint64_t o = topk[m];                    // broadcast read, conflict-free
      rank += (o > key || (o == key && m < tid)) ? 1 : 0;
    }
    unsigned int idx = ~((unsigned int)key);
    if (idx >= 104857600u) idx = 0;           // safety clamp (degenerate only)
    unsigned int s   = idx / 51200u;          // n_r*K*K = 2048*25
    unsigned int rem = idx % 51200u;
    unsigned int r   = rem / 25u;
    unsigned int sij = rem % 25u;
    out[0 * TOPK + rank] = (int)s;                      // first_node_src
    out[1 * TOPK + rank] = (int)r;                      // first_node_ref
    out[2 * TOPK + rank] = sidx[s * NK + sij / 5u];     // second_node_src
    out[3 * TOPK + rank] = ridx[r * NK + sij % 5u];     // second_node_ref
  }
}

extern "C" void kernel_launch(void* const* d_in, const int* in_sizes, int n_in,
                              void* d_out, int out_size, void* d_ws, size_t ws_size,
                              hipStream_t stream) {
  const float* src = (const float*)d_in[0];
  const float* ref = (const float*)d_in[1];
  const float* L   = (const float*)d_in[2];
  char* ws = (char*)d_ws;
  int*          sidx  = (int*)(ws + OFF_SIDX);
  float*        sdist = (float*)(ws + OFF_SDIST);
  int*          ridx  = (int*)(ws + OFF_RIDX);
  float*        rdist = (float*)(ws + OFF_RDIST);
  unsigned int* hist  = (unsigned int*)(ws + OFF_HIST);
  unsigned int* cnts  = (unsigned int*)(ws + OFF_CNT);
  uint64_t*     cand  = (uint64_t*)(ws + OFF_CAND);
  uint64_t*     glist = (uint64_t*)(ws + OFF_GLIST);
  unsigned int* gcnt  = (unsigned int*)(ws + OFF_GCNT);
  int*          out   = (int*)d_out;

  unsigned int cap = 0;
  if (ws_size > (size_t)OFF_CAND + 8) {
    size_t c = (ws_size - (size_t)OFF_CAND) / 8;
    if (c > CAP_MAX) c = CAP_MAX;
    cap = (unsigned int)c;
  }
  const int use_list = (ws_size >= WS_NEED) ? 1 : 0;

  knn_kernel<<<512, 256, 0, stream>>>(src, ref, sidx, sdist, ridx, rdist, hist, cnts);
  lowb_kernel<<<N_PTS, 256, 0, stream>>>(L, sidx, sdist, ridx, rdist, hist,
                                         glist, gcnt, use_list);
  collect_kernel<<<N_PTS, 256, 0, stream>>>(L, sidx, sdist, ridx, rdist, hist,
                                            glist, gcnt, use_list,
                                            cnts, cand, cap);
  select_kernel<<<1, 1024, 0, stream>>>(cand, cnts, sidx, ridx, out, cap);
}

// Round 17
// 158.480 us; speedup vs baseline: 1.0469x; 1.0469x over previous
//
#include <hip/hip_runtime.h>
#include <stdint.h>

#define N_PTS 2048
#define NK 5
#define TOPK 512
#define CAP_MAX 262144u
#define GLIST_CAP 256
#define T0_BITS 0x3F700000u          /* 0.9375f — static list threshold */

// frozen arithmetic (r9-verified bit-exact vs np oracle):
//   d2 = fma(dz,dz, fma(dx,dx, dy*dy)); d = sqrt(max(d2,0))
//   q = fdiv(diff*diff, 0.01f); temp = max(1-q,0); v = (L*temp)*A
// tie rule: value desc, flat idx asc (key (vb<<32)|~idx descending)
// rejection bounds (exact): v <= fmul_rn(Lsr,temp) <= Lsr
// div-free cell pre-gate (exact, RN-monotone):
//   temp <= fma(dsq,-99,1) = ts  =>  RN(Lsr*ts) = ubt >= ub >= v
// latency rule (r4): no gather-dependent value in the gate of the next gather.
// gather rule (r12): gate gathers with a running wave max (exact pruning).
// serialization rule (r5/r16): no serial per-bin scans on one lane; wave-split
//   histograms; ballot-aggregated queue pushes. r16 COROLLARY: an O(N) per-
//   thread broadcast-LDS loop (rank-by-count over 512) is ALSO a serial
//   latency chain — costs MORE than the bitonic's 45 barriers (+7.3us,
//   r11/r16 both). Bitonic stays.
// threshold relaxation (r6/r7/r13): T' = lower edge of the 256-bin
//   lb-histogram bin where the from-top cumulative crosses 512; candidate
//   superset => select's exact top-512 bit-identical. Derived per block in
//   collect; no grid sync.
// launch rule (r7): no cooperative launch / grid.sync under this harness.
// anchor rule (r9/r12): revert to best measured + ONE delta after failure.
// harness floor (r9/r14): ws re-poison fills ~86us/iter (54%, 79% HBM peak)
//   untouchable. collect 21-22us (r14 probe), NOT stream-bound (r15 null).
// balance rule (r10): compact survivors (LDS queue) + cell-parallel.
// fragmentation rule (r13): per-dispatch overhead ~3us — minimize kernels.
// attribution rule (r14/r16): measure or isolate before theorizing; bundled
//   changes must be re-tested one at a time.
// list rule (r15): lowb emits per-row survivor lists at static T0; collect
//   skips its L-stream when T' >= T0 and no overflow; else full-row path.
// floor state (r17): remaining 4 kernels all latency/launch-bound (<42us
//   each); last levers: -2.7, null, -0.75, +7.3(reverted). At floor.

// ws layout (bytes):
//      0  src_ne_idx   int[10240]    (40960)
//  40960  src_ne_dist  f32[10240]    (40960)
//  81920  ref_ne_idx   int[10240]    (40960)
// 122880  ref_ne_dist  f32[10240]    (40960)
// 163840  hist         uint[256]     (1024)  (lb histogram; zeroed by knn)
// 172032  counters     uint[8]       (32)    [0]=cand_count (zeroed by knn)
// 172064  cand         uint64[CAP_MAX]               (2MB)
// 2269216 glist        uint64[2048*GLIST_CAP]        (4MB)  (Lsr<<32|col)
// 6463520 gcnt         uint[2048]                    (8KB)
#define OFF_SIDX   0
#define OFF_SDIST  40960
#define OFF_RIDX   81920
#define OFF_RDIST  122880
#define OFF_HIST   163840
#define OFF_CNT    172032
#define OFF_CAND   172064
#define OFF_GLIST  2269216
#define OFF_GCNT   6463520
#define WS_NEED    6471712ull

__device__ __forceinline__ unsigned long long shflxor64(unsigned long long v, int mask) {
  unsigned lo = (unsigned)v, hi = (unsigned)(v >> 32);
  lo = (unsigned)__shfl_xor((int)lo, mask);
  hi = (unsigned)__shfl_xor((int)hi, mask);
  return ((unsigned long long)hi << 32) | lo;
}

__device__ __forceinline__ int lb_bin(unsigned int bits) {
  int b = (int)(bits >> 16) - 0x3E80;
  return b < 0 ? 0 : (b > 255 ? 255 : b);
}

// ---------------- KNN: 512 blocks, 8 points/block, 32 lanes/point ------------
__global__ __launch_bounds__(256) void knn_kernel(
    const float* __restrict__ src, const float* __restrict__ ref,
    int* __restrict__ sidx, float* __restrict__ sdist,
    int* __restrict__ ridx, float* __restrict__ rdist,
    unsigned int* __restrict__ hist, unsigned int* __restrict__ counters) {
  __shared__ float sx[N_PTS], sy[N_PTS], sz[N_PTS];
  const bool is_ref = blockIdx.x >= 256;
  const float* pts = is_ref ? ref : src;
  int*   oidx  = is_ref ? ridx : sidx;
  float* odist = is_ref ? rdist : sdist;
  const int blk = is_ref ? (blockIdx.x - 256) : blockIdx.x;

  if (blockIdx.x == 0) {
    if (threadIdx.x < 256) hist[threadIdx.x] = 0;
    if (threadIdx.x < 8) counters[threadIdx.x] = 0;
  }

  for (int t = threadIdx.x; t < N_PTS; t += 256) {
    sx[t] = pts[3 * t + 0];
    sy[t] = pts[3 * t + 1];
    sz[t] = pts[3 * t + 2];
  }
  __syncthreads();

  const int p = blk * 8 + (threadIdx.x >> 5);
  const int u = threadIdx.x & 31;
  const float px = sx[p], py = sy[p], pz = sz[p];

  unsigned long long best[6];
#pragma unroll
  for (int k = 0; k < 6; ++k) best[k] = ~0ull;

  for (int j = u; j < N_PTS; j += 32) {
    float dx = __fsub_rn(px, sx[j]);
    float dy = __fsub_rn(py, sy[j]);
    float dz = __fsub_rn(pz, sz[j]);
    float d2 = __builtin_fmaf(dz, dz,
                 __builtin_fmaf(dx, dx, __fmul_rn(dy, dy)));
    float d = __fsqrt_rn(fmaxf(d2, 0.0f));
    unsigned long long key = (((unsigned long long)__float_as_uint(d)) << 32)
                           | (unsigned)j;
    if (key < best[5]) {
      best[5] = key;
#pragma unroll
      for (int k = 5; k >= 1; --k)
        if (best[k] < best[k - 1]) {
          unsigned long long t = best[k]; best[k] = best[k - 1]; best[k - 1] = t;
        }
    }
  }

  int h = 0;
  unsigned long long win[6];
#pragma unroll
  for (int round = 0; round < 6; ++round) {
    unsigned long long my = (h < 6) ? best[h] : ~0ull;
    unsigned long long m = my;
#pragma unroll
    for (int msk = 16; msk >= 1; msk >>= 1) {
      unsigned long long o = shflxor64(m, msk);
      if (o < m) m = o;
    }
    win[round] = m;
    if (my == m) ++h;
  }

  if (u == 0) {
#pragma unroll
    for (int m = 1; m <= NK; ++m) {     // drop win[0] == self (d = 0)
      oidx[p * NK + m - 1]  = (int)(win[m] & 0xFFFFFFFFull);
      odist[p * NK + m - 1] = __uint_as_float((unsigned)(win[m] >> 32));
    }
  }
}

// ---------------- pass 1: lower bound -> histogram, + survivor list (r15) ----
__global__ __launch_bounds__(256) void lowb_kernel(
    const float* __restrict__ L,
    const int* __restrict__ sidx, const float* __restrict__ sdist,
    const int* __restrict__ ridx, const float* __restrict__ rdist,
    unsigned int* __restrict__ hist,
    uint64_t* __restrict__ glist, unsigned int* __restrict__ gcnt,
    int use_list) {
  __shared__ float sdsh[NK];
  __shared__ int   snsh[NK];
  __shared__ unsigned int s_max;
  __shared__ unsigned int lqn;
  const int s = blockIdx.x, tid = threadIdx.x;
  const int lane = tid & 63;
  if (tid < NK) { snsh[tid] = sidx[s * NK + tid]; sdsh[tid] = sdist[s * NK + tid]; }
  if (tid == 0) { s_max = 0; lqn = 0; }
  __syncthreads();                             // lqn=0 visible before pushes
  const float* __restrict__ Lg = L + (size_t)s * N_PTS;
  const float T0f = __uint_as_float(T0_BITS);

  // per-thread top-3 over its 8 contiguous columns + list push
  unsigned long long b0 = 0ull, b1 = 0ull, b2 = 0ull;
  {
    const float4* Lg4 = (const float4*)Lg;
    float4 A0 = Lg4[2 * tid], A1 = Lg4[2 * tid + 1];
    float lv[8] = {A0.x, A0.y, A0.z, A0.w, A1.x, A1.y, A1.z, A1.w};
#pragma unroll
    for (int e = 0; e < 8; ++e) {
      unsigned long long key =
          (((unsigned long long)__float_as_uint(lv[e])) << 32)
          | (unsigned)(tid * 8 + e);           // L >= 0: bit order == value order
      if (key > b0) { b2 = b1; b1 = b0; b0 = key; }
      else if (key > b1) { b2 = b1; b1 = key; }
      else if (key > b2) b2 = key;
      const bool qp = use_list && (lv[e] >= T0f);
      unsigned long long m = __ballot(qp);
      if (qp) {
        const int leader = __ffsll((long long)m) - 1;
        unsigned int base = 0;
        if (lane == leader) base = atomicAdd(&lqn, (unsigned int)__popcll(m));
        base = (unsigned int)__shfl((int)base, leader);
        const unsigned int pos =
            base + (unsigned int)__popcll(m & ((1ull << lane) - 1ull));
        if (pos < GLIST_CAP)
          glist[(size_t)s * GLIST_CAP + pos] =
              (((uint64_t)__float_as_uint(lv[e])) << 32)
              | (uint64_t)(unsigned)(tid * 8 + e);
      }
    }
  }
  __syncthreads();                             // sdsh/snsh + list pushes done

  unsigned int lmw = 0;                        // running wave max (uniform)
  int h = 0;
  for (int round = 0; round < 3; ++round) {
    unsigned long long my = (h == 0) ? b0 : ((h == 1) ? b1 : ((h == 2) ? b2 : 0ull));
    unsigned long long w = my;
#pragma unroll
    for (int msk = 32; msk >= 1; msk >>= 1) {
      unsigned long long o = shflxor64(w, msk);
      if (o > w) w = o;
    }
    if (my == w && w != 0ull) ++h;             // unique keys (r embedded)
    if ((unsigned)(w >> 32) == 0u) continue;
    const int rwin = (int)(w & 0xFFFFFFFFull);
    const float Lsr = __uint_as_float((unsigned)(w >> 32));
    unsigned int vb = 0;
    if (lane < NK * NK) {
      const int i = lane / NK, j = lane - i * NK;
      float diff = __fsub_rn(sdsh[i], rdist[rwin * NK + j]);  // frozen chain
      float dsq  = __fmul_rn(diff, diff);
      if (dsq < 0.0101f) {
        float ts  = __builtin_fmaf(dsq, -99.0f, 1.0f);        // >= temp (exact)
        float ubt = __fmul_rn(Lsr, ts);                       // >= ub >= v
        if (ubt > __uint_as_float(lmw)) {                     // running-max gate
          float q    = __fdiv_rn(dsq, 0.01f);
          float temp = fmaxf(__fsub_rn(1.0f, q), 0.0f);
          if (temp > 0.0f) {
            float ub = __fmul_rn(Lsr, temp);
            float a  = L[(size_t)snsh[i] * N_PTS + ridx[rwin * NK + j]];
            float v  = __fmul_rn(ub, a);                      // frozen chain
            if (v > 0.0f) vb = __float_as_uint(v);
          }
        }
      }
    }
#pragma unroll
    for (int msk = 32; msk >= 1; msk >>= 1) {
      unsigned int o = (unsigned)__shfl_xor((int)vb, msk);
      if (o > vb) vb = o;
    }
    if (vb > lmw) lmw = vb;                    // uniform across wave
  }
  if (lane == 0 && lmw > 0u) atomicMax(&s_max, lmw);
  __syncthreads();
  if (tid == 0) {
    atomicAdd(&hist[lb_bin(s_max)], 1u);
    if (use_list) gcnt[s] = lqn;
  }
}

// ---------------- pass 2: collect — list fast path or full-row (r15/r13) -----
__global__ __launch_bounds__(256) void collect_kernel(
    const float* __restrict__ L,
    const int* __restrict__ sidx, const float* __restrict__ sdist,
    const int* __restrict__ ridx, const float* __restrict__ rdist,
    const unsigned int* __restrict__ hist,
    const uint64_t* __restrict__ glist, const unsigned int* __restrict__ gcnt,
    int use_list,
    unsigned int* __restrict__ cand_count, uint64_t* __restrict__ cand,
    unsigned int cap) {
  __shared__ float sdsh[NK];
  __shared__ int   snsh[NK];
  __shared__ int   q_r[N_PTS];
  __shared__ float q_L[N_PTS];
  __shared__ unsigned int qn;
  __shared__ unsigned int sh_T;
  const int s = blockIdx.x, tid = threadIdx.x;
  const int lane = tid & 63;
  if (tid < NK) { snsh[tid] = sidx[s * NK + tid]; sdsh[tid] = sdist[s * NK + tid]; }
  if (tid == 0) qn = 0;

  // ---- wave 0: derive T' from histogram (r5 scan; crossing always exists) --
  if (tid < 64) {
    const int b0i = tid * 4;
    unsigned int c0 = hist[b0i + 0], c1 = hist[b0i + 1];
    unsigned int c2 = hist[b0i + 2], c3 = hist[b0i + 3];
    const unsigned int S = c0 + c1 + c2 + c3;
    unsigned int si = S;                       // inclusive suffix over lanes
#pragma unroll
    for (int off = 1; off < 64; off <<= 1) {
      unsigned int o = (unsigned)__shfl_down((int)si, off);
      si += (tid + off < 64) ? o : 0u;
    }
    const unsigned int SE = si - S;
    const unsigned int k = TOPK;
    const unsigned int s3 = SE + c3;
    const unsigned int s2 = s3 + c2;
    const unsigned int s1 = s2 + c1;
    const unsigned int s0 = s1 + c0;
    int b = -1;
    if      (s0 >= k && s1 < k) b = b0i + 0;
    else if (s1 >= k && s2 < k) b = b0i + 1;
    else if (s2 >= k && s3 < k) b = b0i + 2;
    else if (s3 >= k && SE < k) b = b0i + 3;
    if (b >= 0)
      sh_T = (b > 0) ? (((unsigned int)(0x3E80 + b)) << 16) : 0u;
  }
  __syncthreads();                             // sh_T, qn, sdsh/snsh visible
  const unsigned int T = sh_T;
  const float T_f = __uint_as_float(T);

  // ---- phase A: build survivor queue (fast: from glist; slow: full row) ----
  const unsigned int gc = use_list ? gcnt[s] : 0xFFFFFFFFu;  // broadcast load
  const bool fast = use_list && (T >= T0_BITS) && (gc <= GLIST_CAP);
  if (fast) {
    bool have = false; int col = 0; float Ls = 0.0f;
    if ((unsigned int)tid < gc) {
      uint64_t e = glist[(size_t)s * GLIST_CAP + tid];
      Ls  = __uint_as_float((unsigned int)(e >> 32));
      col = (int)(unsigned int)(e & 0xFFFFFFFFull);
      have = (Ls >= T_f);                      // exact filter: {r: Lsr >= T'}
    }
    unsigned long long m = __ballot(have);
    if (have) {
      const int leader = __ffsll((long long)m) - 1;
      unsigned int base = 0;
      if (lane == leader) base = atomicAdd(&qn, (unsigned int)__popcll(m));
      base = (unsigned int)__shfl((int)base, leader);
      const unsigned int off =
          (unsigned int)__popcll(m & ((1ull << lane) - 1ull));
      q_r[base + off] = col;
      q_L[base + off] = Ls;
    }
  } else {
    const float4* Lg4 = (const float4*)(L + (size_t)s * N_PTS);
    float4 A0 = Lg4[2 * tid], A1 = Lg4[2 * tid + 1];
    float lv[8] = {A0.x, A0.y, A0.z, A0.w, A1.x, A1.y, A1.z, A1.w};
#pragma unroll
    for (int e = 0; e < 8; ++e) {
      const float Lsr = lv[e];
      const bool surv = (Lsr >= T_f);          // v <= Lsr < T' => reject rest
      unsigned long long mask = __ballot(surv);
      if (surv) {
        const int leader = __ffsll((long long)mask) - 1;
        unsigned int base = 0;
        if (lane == leader) base = atomicAdd(&qn, (unsigned int)__popcll(mask));
        base = (unsigned int)__shfl((int)base, leader);
        const unsigned int off =
            (unsigned int)__popcll(mask & ((1ull << lane) - 1ull));
        q_r[base + off] = tid * 8 + e;
        q_L[base + off] = Lsr;
      }
    }
  }
  __syncthreads();
  const unsigned int nq = qn;

  // ---- phase B: cell-parallel processing, 8 groups x 32 lanes ----
  const int g = tid >> 5, l32 = tid & 31;
  const bool cell = (l32 < NK * NK);
  const int ci = cell ? (l32 / NK) : 0;
  const int cj = cell ? (l32 - ci * NK) : 0;
  const float sd_i = sdsh[ci];
  const float* __restrict__ Arow = L + (size_t)snsh[ci] * N_PTS;

  for (unsigned int base = 0; base < nq; base += 8) {
    const unsigned int qi = base + (unsigned int)g;
    if (qi >= nq) break;                       // group-uniform; no barriers here
    const int r = q_r[qi];
    const float Lsr = q_L[qi];
    if (cell) {
      float rdv  = rdist[r * NK + cj];
      float diff = __fsub_rn(sd_i, rdv);
      float dsq  = __fmul_rn(diff, diff);
      if (dsq < 0.0101f) {                               // else temp provably 0
        float ts  = __builtin_fmaf(dsq, -99.0f, 1.0f);   // >= temp (exact)
        float ubt = __fmul_rn(Lsr, ts);                  // >= ub >= v
        if (ubt >= T_f) {                                // div-free pre-gate
          float q    = __fdiv_rn(dsq, 0.01f);
          float temp = fmaxf(__fsub_rn(1.0f, q), 0.0f);
          if (temp > 0.0f) {
            float ub = __fmul_rn(Lsr, temp);
            if (ub >= T_f) {                             // v <= ub < T' reject
              int   rn = ridx[r * NK + cj];
              float v  = __fmul_rn(ub, Arow[rn]);        // frozen chain
              unsigned int vb = __float_as_uint(v);
              if (v > 0.0f && vb >= T) {
                unsigned int pos = atomicAdd(cand_count, 1u);
                if (pos < cap) {
                  unsigned int idx = ((unsigned int)s * (unsigned int)N_PTS
                                      + (unsigned int)r) * 25u
                                   + (unsigned int)ci * 5u + (unsigned int)cj;
                  cand[pos] = (((uint64_t)vb) << 32)
                            | (uint64_t)((uint32_t)(~idx));
                }
              }
            }
          }
        }
      }
    }
  }
}

// ---------------- exact top-512: byte radix-select + bitonic sort ------------
// r5: 16-way wave-split histogram + wave-0 register suffix-scan bin select.
// r16: rank-by-count REFUTED (+7.3us) — bitonic's 45 barriers beat a 512-
// iteration per-thread broadcast loop. Bitonic retained.
__global__ __launch_bounds__(1024) void select_kernel(
    const uint64_t* __restrict__ cand, const unsigned int* __restrict__ counters,
    const int* __restrict__ sidx, const int* __restrict__ ridx,
    int* __restrict__ out, unsigned int cap) {
  __shared__ unsigned int h[16][257];          // wave-split histogram, padded
  __shared__ uint64_t topk[TOPK];
  __shared__ unsigned int cnt2;
  __shared__ uint64_t sh_prefix;
  __shared__ unsigned int sh_k;
  const int tid = threadIdx.x;
  const int wv = tid >> 6;
  unsigned int n = counters[0];
  if (n > cap) n = cap;
  if (tid == 0) { sh_prefix = 0; sh_k = TOPK; cnt2 = 0; }
  unsigned int* hflat = &h[0][0];

  for (int byte = 7; byte >= 0; --byte) {
    for (int t = tid; t < 16 * 257; t += 1024) hflat[t] = 0;
    __syncthreads();
    const uint64_t prefix = sh_prefix;
    const uint64_t mask = (byte == 7) ? 0ull : (~0ull << (8 * (byte + 1)));
    for (unsigned int i = tid; i < n; i += 1024) {
      uint64_t key = cand[i];
      if ((key & mask) == prefix)
        atomicAdd(&h[wv][(unsigned int)(key >> (8 * byte)) & 255u], 1u);
    }
    __syncthreads();
    if (tid < 64) {                            // wave 0: parallel bin select
      const int b0i = tid * 4;
      unsigned int c0 = 0, c1 = 0, c2 = 0, c3 = 0;
#pragma unroll
      for (int w = 0; w < 16; ++w) {
        c0 += h[w][b0i + 0]; c1 += h[w][b0i + 1];
        c2 += h[w][b0i + 2]; c3 += h[w][b0i + 3];
      }
      const unsigned int S = c0 + c1 + c2 + c3;
      unsigned int si = S;                     // inclusive suffix over lanes
#pragma unroll
      for (int off = 1; off < 64; off <<= 1) {
        unsigned int o = (unsigned)__shfl_down((int)si, off);
        si += (tid + off < 64) ? o : 0u;
      }
      const unsigned int SE = si - S;          // suffix-exclusive of this lane
      const unsigned int k = sh_k;
      const unsigned int s3 = SE + c3;
      const unsigned int s2 = s3 + c2;
      const unsigned int s1 = s2 + c1;
      const unsigned int s0 = s1 + c0;
      int b = -1; unsigned int kn = 0;
      if      (s0 >= k && s1 < k) { b = b0i + 0; kn = k - s1; }
      else if (s1 >= k && s2 < k) { b = b0i + 1; kn = k - s2; }
      else if (s2 >= k && s3 < k) { b = b0i + 2; kn = k - s3; }
      else if (s3 >= k && SE < k) { b = b0i + 3; kn = k - SE; }
      unsigned long long bal = __ballot(b >= 0);
      if (b >= 0) {
        sh_prefix = prefix | (((uint64_t)(unsigned)b) << (8 * byte));
        sh_k = kn;
      } else if (tid == 0 && bal == 0ull) {
        sh_prefix = prefix;                    // degenerate: chosen=0, k kept
      }
    }
    __syncthreads();
  }
  const uint64_t kstar = sh_prefix;

  for (int t = tid; t < TOPK; t += 1024) topk[t] = 0;
  __syncthreads();
  for (unsigned int i = tid; i < n; i += 1024) {
    uint64_t key = cand[i];
    if (key >= kstar) {
      unsigned int pos = atomicAdd(&cnt2, 1u);
      if (pos < TOPK) topk[pos] = key;
    }
  }
  __syncthreads();

  for (int k2 = 2; k2 <= TOPK; k2 <<= 1) {
    for (int j2 = k2 >> 1; j2 > 0; j2 >>= 1) {
      if (tid < TOPK) {
        int ixj = tid ^ j2;
        if (ixj > tid) {
          bool asc = ((tid & k2) == 0);
          uint64_t a = topk[tid], b = topk[ixj];
          if (asc ? (a < b) : (a > b)) { topk[tid] = b; topk[ixj] = a; }
        }
      }
      __syncthreads();
    }
  }

  if (tid < TOPK) {
    uint64_t key = topk[tid];
    unsigned int idx = ~((unsigned int)key);
    if (idx >= 104857600u) idx = 0;           // safety clamp (degenerate only)
    unsigned int s   = idx / 51200u;          // n_r*K*K = 2048*25
    unsigned int rem = idx % 51200u;
    unsigned int r   = rem / 25u;
    unsigned int sij = rem % 25u;
    out[0 * TOPK + tid] = (int)s;                       // first_node_src
    out[1 * TOPK + tid] = (int)r;                       // first_node_ref
    out[2 * TOPK + tid] = sidx[s * NK + sij / 5u];      // second_node_src
    out[3 * TOPK + tid] = ridx[r * NK + sij % 5u];      // second_node_ref
  }
}

extern "C" void kernel_launch(void* const* d_in, const int* in_sizes, int n_in,
                              void* d_out, int out_size, void* d_ws, size_t ws_size,
                              hipStream_t stream) {
  const float* src = (const float*)d_in[0];
  const float* ref = (const float*)d_in[1];
  const float* L   = (const float*)d_in[2];
  char* ws = (char*)d_ws;
  int*          sidx  = (int*)(ws + OFF_SIDX);
  float*        sdist = (float*)(ws + OFF_SDIST);
  int*          ridx  = (int*)(ws + OFF_RIDX);
  float*        rdist = (float*)(ws + OFF_RDIST);
  unsigned int* hist  = (unsigned int*)(ws + OFF_HIST);
  unsigned int* cnts  = (unsigned int*)(ws + OFF_CNT);
  uint64_t*     cand  = (uint64_t*)(ws + OFF_CAND);
  uint64_t*     glist = (uint64_t*)(ws + OFF_GLIST);
  unsigned int* gcnt  = (unsigned int*)(ws + OFF_GCNT);
  int*          out   = (int*)d_out;

  unsigned int cap = 0;
  if (ws_size > (size_t)OFF_CAND + 8) {
    size_t c = (ws_size - (size_t)OFF_CAND) / 8;
    if (c > CAP_MAX) c = CAP_MAX;
    cap = (unsigned int)c;
  }
  const int use_list = (ws_size >= WS_NEED) ? 1 : 0;

  knn_kernel<<<512, 256, 0, stream>>>(src, ref, sidx, sdist, ridx, rdist, hist, cnts);
  lowb_kernel<<<N_PTS, 256, 0, stream>>>(L, sidx, sdist, ridx, rdist, hist,
                                         glist, gcnt, use_list);
  collect_kernel<<<N_PTS, 256, 0, stream>>>(L, sidx, sdist, ridx, rdist, hist,
                                            glist, gcnt, use_list,
                                            cnts, cand, cap);
  select_kernel<<<1, 1024, 0, stream>>>(cand, cnts, sidx, ridx, out, cap);
}